// Round 3
// baseline (366.002 us; speedup 1.0000x reference)
//
#include <hip/hip_runtime.h>
#include <math.h>
#include <float.h>

// Problem constants (fixed by the reference)
#define Bn   64
#define Sn   512
#define En   128
#define Hn   128
#define G4   512     // 4*H
#define FWn  6
#define Wn   507     // S - FW + 1
#define NTILE 16     // 507 windows -> 16 tiles of 32

typedef __attribute__((ext_vector_type(8))) _Float16 half8;
typedef __attribute__((ext_vector_type(4))) float f32x4;

// Fast activations: v_exp_f32 + v_rcp_f32 (1 ulp), NaN-free at extremes.
__device__ __forceinline__ float sigf(float x)  {
    return __builtin_amdgcn_rcpf(1.0f + __expf(-x));
}
__device__ __forceinline__ float tanh_(float x) {
    return 1.0f - 2.0f * __builtin_amdgcn_rcpf(__expf(2.0f * x) + 1.0f);
}

// ---------------------------------------------------------------------------
// Kernel 0: pack w_ih and w_hh (both [512][128] f32) into fp16 B-fragment
// order for mfma_f32_16x16x32_f16:
//   pack[((nt*4 + ks)*64 + lane)*8 + j] = w[nt*16 + (lane&15)][ks*32 + (lane>>4)*8 + j]
// Row-tile nt = g*8 + ut (gate g, unit-tile ut). 65536 elements each.
// ---------------------------------------------------------------------------
__global__ void __launch_bounds__(256)
pack_w_kernel(const float* __restrict__ w_ih, const float* __restrict__ w_hh,
              _Float16* __restrict__ wih_p, _Float16* __restrict__ whh_p)
{
    const int idx = blockIdx.x * 256 + threadIdx.x;      // 0..65535
    const int j  = idx & 7;
    const int L  = (idx >> 3) & 63;
    const int ks = (idx >> 9) & 3;
    const int nt = idx >> 11;
    const int row = nt * 16 + (L & 15);
    const int col = ks * 32 + (L >> 4) * 8 + j;
    wih_p[idx] = (_Float16)w_ih[row * 128 + col];
    whh_p[idx] = (_Float16)w_hh[row * 128 + col];
}

// ---------------------------------------------------------------------------
// Kernel 1 (MFMA): P2[n][u][g] = embed[inputs[n]] . w_ih[g*128+u] + bias
//   Gate-interleaved layout: float4 per (token, unit) = {i,f,g,o}.
//   32 tokens (2 M-tiles) per block; wave wv owns unit-tiles {2wv, 2wv+1},
//   computing all 4 gate row-tiles per unit-tile -> float4 stores.
// grid 1024, block 256
// ---------------------------------------------------------------------------
__global__ void __launch_bounds__(256, 4)
proj_kernel(const int* __restrict__ inputs, const float* __restrict__ embed,
            const _Float16* __restrict__ wih_p, const float* __restrict__ b_ih,
            const float* __restrict__ b_hh, float* __restrict__ P)
{
    const int t  = threadIdx.x;
    const int L  = t & 63;
    const int wv = t >> 6;
    const int n0 = blockIdx.x * 32;
    const int q  = L >> 4;
    const int ln = L & 15;

    // A fragments: A[m = L&15][k = q*8 + j], m-tile mt, k-tile ks
    half8 A[2][4];
#pragma unroll
    for (int mt = 0; mt < 2; ++mt) {
        const int tok = inputs[n0 + mt * 16 + ln];
        const float* __restrict__ er = embed + (size_t)tok * 128 + q * 8;
#pragma unroll
        for (int ks = 0; ks < 4; ++ks) {
            float4 e0 = *(const float4*)(er + ks * 32);
            float4 e1 = *(const float4*)(er + ks * 32 + 4);
            half8 a;
            a[0] = (_Float16)e0.x; a[1] = (_Float16)e0.y;
            a[2] = (_Float16)e0.z; a[3] = (_Float16)e0.w;
            a[4] = (_Float16)e1.x; a[5] = (_Float16)e1.y;
            a[6] = (_Float16)e1.z; a[7] = (_Float16)e1.w;
            A[mt][ks] = a;
        }
    }

#pragma unroll
    for (int uti = 0; uti < 2; ++uti) {
        const int ut = wv * 2 + uti;
        f32x4 acc[2][4];   // [mt][gate]
#pragma unroll
        for (int mt = 0; mt < 2; ++mt)
#pragma unroll
            for (int g = 0; g < 4; ++g) acc[mt][g] = (f32x4){0.f, 0.f, 0.f, 0.f};
#pragma unroll
        for (int ks = 0; ks < 4; ++ks)
#pragma unroll
            for (int g = 0; g < 4; ++g) {
                const int nt = g * 8 + ut;
                half8 bf = *(const half8*)(wih_p + ((size_t)(nt * 4 + ks) * 64 + L) * 8);
                acc[0][g] = __builtin_amdgcn_mfma_f32_16x16x32_f16(A[0][ks], bf, acc[0][g], 0, 0, 0);
                acc[1][g] = __builtin_amdgcn_mfma_f32_16x16x32_f16(A[1][ks], bf, acc[1][g], 0, 0, 0);
            }
        const int u = ut * 16 + ln;
        float4 bias;
        bias.x = b_ih[u]       + b_hh[u];
        bias.y = b_ih[128 + u] + b_hh[128 + u];
        bias.z = b_ih[256 + u] + b_hh[256 + u];
        bias.w = b_ih[384 + u] + b_hh[384 + u];
#pragma unroll
        for (int mt = 0; mt < 2; ++mt)
#pragma unroll
            for (int r = 0; r < 4; ++r) {
                const int row = n0 + mt * 16 + q * 4 + r;
                float4 o = {acc[mt][0][r] + bias.x, acc[mt][1][r] + bias.y,
                            acc[mt][2][r] + bias.z, acc[mt][3][r] + bias.w};
                *(float4*)(P + (size_t)row * G4 + u * 4) = o;
            }
    }
}

// ---------------------------------------------------------------------------
// Kernel 2 (MFMA LSTM): 32 windows per block, 6 steps, h in LDS pre-swizzled
// to A-fragment order (double-buffered, 1 barrier/step). C initialized from
// gate-interleaved fp32 P (float4 per (row,unit)); w_hh B-fragments streamed
// from packed fp16 (L2-resident).
// grid 64*16, block 256
// ---------------------------------------------------------------------------
__global__ void __launch_bounds__(256, 4)
lstm_kernel(const float* __restrict__ P, const _Float16* __restrict__ whh_p,
            float* __restrict__ partial)
{
    __shared__ _Float16 hsA[2][4096];   // 2 x 8 KB, A-fragment order
    const int t    = threadIdx.x;
    const int L    = t & 63;
    const int wv   = t >> 6;
    const int b    = blockIdx.x >> 4;
    const int tile = blockIdx.x & 15;
    const int w0   = tile * 32;
    const float* __restrict__ Pb = P + (size_t)b * Sn * G4;
    const int q  = L >> 4;
    const int ln = L & 15;
    const int j8 = L & 7;

    float cst[2][2][4];    // [uti][mt][r]
    float hcur[2][2][4];

    // base window index per (mt, r) slot
    // s(st) = min(w0 + mt*16 + q*4 + r + st, 511)

    // ---- step 0: h = 0 -> gates = P row; f-gate drops (c0 = 0) ----
#pragma unroll
    for (int uti = 0; uti < 2; ++uti) {
        const int u = (wv * 2 + uti) * 16 + ln;
#pragma unroll
        for (int mt = 0; mt < 2; ++mt)
#pragma unroll
            for (int r = 0; r < 4; ++r) {
                int s = w0 + mt * 16 + q * 4 + r;
                s = s < 511 ? s : 511;                 // clamp (masked at max)
                float4 pv = *(const float4*)(Pb + (size_t)s * G4 + u * 4);
                float cc = sigf(pv.x) * tanh_(pv.z);
                cst[uti][mt][r]  = cc;
                hcur[uti][mt][r] = sigf(pv.w) * tanh_(cc);
            }
    }
    // scatter h -> A-frag layout, buffer 0
    {
        _Float16* buf = hsA[0];
#pragma unroll
        for (int uti = 0; uti < 2; ++uti) {
            const int ut = wv * 2 + uti;
            const int ks = ut >> 1;
            const int lamb = 16 * ((ut & 1) * 2 + (ln >> 3));
#pragma unroll
            for (int mt = 0; mt < 2; ++mt)
#pragma unroll
                for (int r = 0; r < 4; ++r)
                    buf[((mt * 4 + ks) * 64 + (q * 4 + r + lamb)) * 8 + j8] =
                        (_Float16)hcur[uti][mt][r];
        }
    }

    // ---- steps 1..5 ----
    for (int st = 1; st < FWn; ++st) {
        __syncthreads();                    // h writes of previous step visible
        const _Float16* hb = hsA[(st - 1) & 1];
        half8 A[2][4];
#pragma unroll
        for (int mt = 0; mt < 2; ++mt)
#pragma unroll
            for (int ks = 0; ks < 4; ++ks)
                A[mt][ks] = *(const half8*)(hb + ((mt * 4 + ks) * 64 + L) * 8);

#pragma unroll
        for (int uti = 0; uti < 2; ++uti) {
            const int ut = wv * 2 + uti;
            const int u  = ut * 16 + ln;
            f32x4 acc[2][4];                // [mt][gate]
            // C init from fp32 gate-interleaved P (full-precision projection)
#pragma unroll
            for (int mt = 0; mt < 2; ++mt)
#pragma unroll
                for (int r = 0; r < 4; ++r) {
                    int s = w0 + mt * 16 + q * 4 + r + st;
                    s = s < 511 ? s : 511;
                    float4 pv = *(const float4*)(Pb + (size_t)s * G4 + u * 4);
                    acc[mt][0][r] = pv.x;
                    acc[mt][1][r] = pv.y;
                    acc[mt][2][r] = pv.z;
                    acc[mt][3][r] = pv.w;
                }
#pragma unroll
            for (int ks = 0; ks < 4; ++ks) {
#pragma unroll
                for (int g = 0; g < 4; ++g) {
                    const int nt = g * 8 + ut;
                    half8 bf = *(const half8*)(whh_p + ((size_t)(nt * 4 + ks) * 64 + L) * 8);
                    acc[0][g] = __builtin_amdgcn_mfma_f32_16x16x32_f16(A[0][ks], bf, acc[0][g], 0, 0, 0);
                    acc[1][g] = __builtin_amdgcn_mfma_f32_16x16x32_f16(A[1][ks], bf, acc[1][g], 0, 0, 0);
                }
            }
            // gate nonlinearity + state update
#pragma unroll
            for (int mt = 0; mt < 2; ++mt)
#pragma unroll
                for (int r = 0; r < 4; ++r) {
                    float ii = sigf(acc[mt][0][r]);
                    float ff = sigf(acc[mt][1][r]);
                    float gg = tanh_(acc[mt][2][r]);
                    float oo = sigf(acc[mt][3][r]);
                    float cc = ff * cst[uti][mt][r] + ii * gg;
                    cst[uti][mt][r]  = cc;
                    hcur[uti][mt][r] = oo * tanh_(cc);
                }
        }
        if (st < FWn - 1) {
            _Float16* buf = hsA[st & 1];    // other buffer: no barrier needed here
#pragma unroll
            for (int uti = 0; uti < 2; ++uti) {
                const int ut = wv * 2 + uti;
                const int ks = ut >> 1;
                const int lamb = 16 * ((ut & 1) * 2 + (ln >> 3));
#pragma unroll
                for (int mt = 0; mt < 2; ++mt)
#pragma unroll
                    for (int r = 0; r < 4; ++r)
                        buf[((mt * 4 + ks) * 64 + (q * 4 + r + lamb)) * 8 + j8] =
                            (_Float16)hcur[uti][mt][r];
            }
        }
    }

    // ---- max over windows (mask invalid), reduce across quads ----
#pragma unroll
    for (int uti = 0; uti < 2; ++uti) {
        float mv = -FLT_MAX;
#pragma unroll
        for (int mt = 0; mt < 2; ++mt)
#pragma unroll
            for (int r = 0; r < 4; ++r) {
                const int w = w0 + mt * 16 + q * 4 + r;
                float hv = (w < Wn) ? hcur[uti][mt][r] : -FLT_MAX;
                mv = fmaxf(mv, hv);
            }
        mv = fmaxf(mv, __shfl_xor(mv, 16));
        mv = fmaxf(mv, __shfl_xor(mv, 32));
        if (q == 0)
            partial[(size_t)(b * NTILE + tile) * 128 + (wv * 2 + uti) * 16 + ln] = mv;
    }
}

// ---------------------------------------------------------------------------
// Kernel 3: feat[b][u] = max over tiles; out[b][c] = feat . fc_w[c] + fc_b[c]
// grid 64, block 128
// ---------------------------------------------------------------------------
__global__ void __launch_bounds__(128)
final_kernel(const float* __restrict__ partial, const float* __restrict__ fc_w,
             const float* __restrict__ fc_b, float* __restrict__ out)
{
    const int b = blockIdx.x;
    const int u = threadIdx.x;
    float m = -FLT_MAX;
#pragma unroll
    for (int tl = 0; tl < NTILE; ++tl)
        m = fmaxf(m, partial[(size_t)(b * NTILE + tl) * 128 + u]);
    float v0 = m * fc_w[u];
    float v1 = m * fc_w[128 + u];
#pragma unroll
    for (int off = 1; off < 64; off <<= 1) {
        v0 += __shfl_xor(v0, off);
        v1 += __shfl_xor(v1, off);
    }
    __shared__ float red[2][2];
    if ((u & 63) == 0) { red[u >> 6][0] = v0; red[u >> 6][1] = v1; }
    __syncthreads();
    if (u == 0) {
        out[b * 2 + 0] = red[0][0] + red[1][0] + fc_b[0];
        out[b * 2 + 1] = red[0][1] + red[1][1] + fc_b[1];
    }
}

// ---------------------------------------------------------------------------
extern "C" void kernel_launch(void* const* d_in, const int* in_sizes, int n_in,
                              void* d_out, int out_size, void* d_ws, size_t ws_size,
                              hipStream_t stream)
{
    const int*   inputs = (const int*)d_in[0];
    // d_in[1] = lengths : unused by the reference
    const float* embed  = (const float*)d_in[2];
    const float* w_ih   = (const float*)d_in[3];
    const float* w_hh   = (const float*)d_in[4];
    const float* b_ih   = (const float*)d_in[5];
    const float* b_hh   = (const float*)d_in[6];
    const float* fc_w   = (const float*)d_in[7];
    const float* fc_b   = (const float*)d_in[8];
    float* out = (float*)d_out;

    // workspace: P [32768][512] f32 (64 MiB) | partial (512 KiB) | packs (2x128 KiB)
    float*    P       = (float*)d_ws;
    float*    partial = P + (size_t)(Bn * Sn) * G4;
    _Float16* wih_p   = (_Float16*)(partial + Bn * NTILE * 128);
    _Float16* whh_p   = wih_p + 65536;

    pack_w_kernel<<<dim3(256), 256, 0, stream>>>(w_ih, w_hh, wih_p, whh_p);
    proj_kernel<<<dim3((Bn * Sn) / 32), 256, 0, stream>>>(inputs, embed, wih_p, b_ih, b_hh, P);
    lstm_kernel<<<dim3(Bn * NTILE), 256, 0, stream>>>(P, whh_p, partial);
    final_kernel<<<dim3(Bn), 128, 0, stream>>>(partial, fc_w, fc_b, out);
}

// Round 4
// 177.283 us; speedup vs baseline: 2.0645x; 2.0645x over previous
//
#include <hip/hip_runtime.h>
#include <math.h>
#include <float.h>

// Problem constants (fixed by the reference)
#define Bn   64
#define Sn   512
#define En   128
#define Hn   128
#define G4   512     // 4*H
#define FWn  6
#define Wn   507     // S - FW + 1
#define NTILE 16     // 507 windows -> 16 tiles of 32

typedef __attribute__((ext_vector_type(8))) _Float16 half8;
typedef __attribute__((ext_vector_type(4))) float f32x4;

// Fast activations: v_exp_f32 + v_rcp_f32 (1 ulp), NaN-free at extremes.
__device__ __forceinline__ float sigf(float x)  {
    return __builtin_amdgcn_rcpf(1.0f + __expf(-x));
}
__device__ __forceinline__ float tanh_(float x) {
    return 1.0f - 2.0f * __builtin_amdgcn_rcpf(__expf(2.0f * x) + 1.0f);
}

// ---------------------------------------------------------------------------
// Kernel 0: pack w_ih and w_hh (both [512][128] f32) into fp16 B-fragment
// order for mfma_f32_16x16x32_f16:
//   pack[((nt*4 + ks)*64 + lane)*8 + j] = w[nt*16 + (lane&15)][ks*32 + (lane>>4)*8 + j]
// Row-tile nt = g*8 + ut (gate g, unit-tile ut). 65536 elements each.
// ---------------------------------------------------------------------------
__global__ void __launch_bounds__(256)
pack_w_kernel(const float* __restrict__ w_ih, const float* __restrict__ w_hh,
              _Float16* __restrict__ wih_p, _Float16* __restrict__ whh_p)
{
    const int idx = blockIdx.x * 256 + threadIdx.x;      // 0..65535
    const int j  = idx & 7;
    const int L  = (idx >> 3) & 63;
    const int ks = (idx >> 9) & 3;
    const int nt = idx >> 11;
    const int row = nt * 16 + (L & 15);
    const int col = ks * 32 + (L >> 4) * 8 + j;
    wih_p[idx] = (_Float16)w_ih[row * 128 + col];
    whh_p[idx] = (_Float16)w_hh[row * 128 + col];
}

// ---------------------------------------------------------------------------
// Kernel 1 (MFMA): P[n][u][g] = embed[inputs[n]] . w_ih[g*128+u] + bias
//   Gate-interleaved layout: float4 per (token, unit) = {i,f,g,o}.
//   32 tokens (2 M-tiles) per block; wave wv owns unit-tiles {2wv, 2wv+1},
//   computing all 4 gate row-tiles per unit-tile -> float4 stores.
// grid 1024, block 256.  NOTE: no min-waves launch bound — R3 showed a
// forced VGPR cap (144->64) causes catastrophic scratch spill (251 MB).
// ---------------------------------------------------------------------------
__global__ void __launch_bounds__(256)
proj_kernel(const int* __restrict__ inputs, const float* __restrict__ embed,
            const _Float16* __restrict__ wih_p, const float* __restrict__ b_ih,
            const float* __restrict__ b_hh, float* __restrict__ P)
{
    const int t  = threadIdx.x;
    const int L  = t & 63;
    const int wv = t >> 6;
    const int n0 = blockIdx.x * 32;
    const int q  = L >> 4;
    const int ln = L & 15;

    // A fragments: A[m = L&15][k = q*8 + j], m-tile mt, k-tile ks
    half8 A[2][4];
#pragma unroll
    for (int mt = 0; mt < 2; ++mt) {
        const int tok = inputs[n0 + mt * 16 + ln];
        const float* __restrict__ er = embed + (size_t)tok * 128 + q * 8;
#pragma unroll
        for (int ks = 0; ks < 4; ++ks) {
            float4 e0 = *(const float4*)(er + ks * 32);
            float4 e1 = *(const float4*)(er + ks * 32 + 4);
            half8 a;
            a[0] = (_Float16)e0.x; a[1] = (_Float16)e0.y;
            a[2] = (_Float16)e0.z; a[3] = (_Float16)e0.w;
            a[4] = (_Float16)e1.x; a[5] = (_Float16)e1.y;
            a[6] = (_Float16)e1.z; a[7] = (_Float16)e1.w;
            A[mt][ks] = a;
        }
    }

#pragma unroll
    for (int uti = 0; uti < 2; ++uti) {
        const int ut = wv * 2 + uti;
        f32x4 acc[2][4];   // [mt][gate]
#pragma unroll
        for (int mt = 0; mt < 2; ++mt)
#pragma unroll
            for (int g = 0; g < 4; ++g) acc[mt][g] = (f32x4){0.f, 0.f, 0.f, 0.f};
#pragma unroll
        for (int ks = 0; ks < 4; ++ks)
#pragma unroll
            for (int g = 0; g < 4; ++g) {
                const int nt = g * 8 + ut;
                half8 bf = *(const half8*)(wih_p + ((size_t)(nt * 4 + ks) * 64 + L) * 8);
                acc[0][g] = __builtin_amdgcn_mfma_f32_16x16x32_f16(A[0][ks], bf, acc[0][g], 0, 0, 0);
                acc[1][g] = __builtin_amdgcn_mfma_f32_16x16x32_f16(A[1][ks], bf, acc[1][g], 0, 0, 0);
            }
        const int u = ut * 16 + ln;
        float4 bias;
        bias.x = b_ih[u]       + b_hh[u];
        bias.y = b_ih[128 + u] + b_hh[128 + u];
        bias.z = b_ih[256 + u] + b_hh[256 + u];
        bias.w = b_ih[384 + u] + b_hh[384 + u];
#pragma unroll
        for (int mt = 0; mt < 2; ++mt)
#pragma unroll
            for (int r = 0; r < 4; ++r) {
                const int row = n0 + mt * 16 + q * 4 + r;
                float4 o = {acc[mt][0][r] + bias.x, acc[mt][1][r] + bias.y,
                            acc[mt][2][r] + bias.z, acc[mt][3][r] + bias.w};
                *(float4*)(P + (size_t)row * G4 + u * 4) = o;
            }
    }
}

// ---------------------------------------------------------------------------
// Kernel 2 (MFMA LSTM): 32 windows per block, 6 steps, h in LDS pre-swizzled
// to A-fragment order (double-buffered, 1 barrier/step). C initialized from
// gate-interleaved fp32 P (float4 per (row,unit)); w_hh B-fragments streamed
// from packed fp16 (L2-resident).
// XCD swizzle: all 16 tiles of a batch land on one XCD so its 4 MB L2 holds
// that batch's 1 MB P slice (plus whh_p 128 KB) across the block's lifetime.
// grid 64*16, block 256.
// ---------------------------------------------------------------------------
__global__ void __launch_bounds__(256)
lstm_kernel(const float* __restrict__ P, const _Float16* __restrict__ whh_p,
            float* __restrict__ partial)
{
    __shared__ _Float16 hsA[2][4096];   // 2 x 8 KB, A-fragment order
    const int t    = threadIdx.x;
    const int L    = t & 63;
    const int wv   = t >> 6;
    // XCD-aware decode: consecutive blockIdx round-robin across 8 XCDs.
    const int xcd  = blockIdx.x & 7;
    const int grp  = blockIdx.x >> 3;          // 0..127
    const int b    = xcd + 8 * (grp >> 4);     // 0..63
    const int tile = grp & 15;                 // 0..15
    const int w0   = tile * 32;
    const float* __restrict__ Pb = P + (size_t)b * Sn * G4;
    const int q  = L >> 4;
    const int ln = L & 15;
    const int j8 = L & 7;

    float cst[2][2][4];    // [uti][mt][r]
    float hcur[2][2][4];

    // ---- step 0: h = 0 -> gates = P row; f-gate drops (c0 = 0) ----
#pragma unroll
    for (int uti = 0; uti < 2; ++uti) {
        const int u = (wv * 2 + uti) * 16 + ln;
#pragma unroll
        for (int mt = 0; mt < 2; ++mt)
#pragma unroll
            for (int r = 0; r < 4; ++r) {
                int s = w0 + mt * 16 + q * 4 + r;
                s = s < 511 ? s : 511;                 // clamp (masked at max)
                float4 pv = *(const float4*)(Pb + (size_t)s * G4 + u * 4);
                float cc = sigf(pv.x) * tanh_(pv.z);
                cst[uti][mt][r]  = cc;
                hcur[uti][mt][r] = sigf(pv.w) * tanh_(cc);
            }
    }
    // scatter h -> A-frag layout, buffer 0
    {
        _Float16* buf = hsA[0];
#pragma unroll
        for (int uti = 0; uti < 2; ++uti) {
            const int ut = wv * 2 + uti;
            const int ks = ut >> 1;
            const int lamb = 16 * ((ut & 1) * 2 + (ln >> 3));
#pragma unroll
            for (int mt = 0; mt < 2; ++mt)
#pragma unroll
                for (int r = 0; r < 4; ++r)
                    buf[((mt * 4 + ks) * 64 + (q * 4 + r + lamb)) * 8 + j8] =
                        (_Float16)hcur[uti][mt][r];
        }
    }

    // ---- steps 1..5 ----
    for (int st = 1; st < FWn; ++st) {
        __syncthreads();                    // h writes of previous step visible
        const _Float16* hb = hsA[(st - 1) & 1];
        half8 A[2][4];
#pragma unroll
        for (int mt = 0; mt < 2; ++mt)
#pragma unroll
            for (int ks = 0; ks < 4; ++ks)
                A[mt][ks] = *(const half8*)(hb + ((mt * 4 + ks) * 64 + L) * 8);

#pragma unroll
        for (int uti = 0; uti < 2; ++uti) {
            const int ut = wv * 2 + uti;
            const int u  = ut * 16 + ln;
            f32x4 acc[2][4];                // [mt][gate]
            // C init from fp32 gate-interleaved P (full-precision projection)
#pragma unroll
            for (int mt = 0; mt < 2; ++mt)
#pragma unroll
                for (int r = 0; r < 4; ++r) {
                    int s = w0 + mt * 16 + q * 4 + r + st;
                    s = s < 511 ? s : 511;
                    float4 pv = *(const float4*)(Pb + (size_t)s * G4 + u * 4);
                    acc[mt][0][r] = pv.x;
                    acc[mt][1][r] = pv.y;
                    acc[mt][2][r] = pv.z;
                    acc[mt][3][r] = pv.w;
                }
#pragma unroll
            for (int ks = 0; ks < 4; ++ks) {
#pragma unroll
                for (int g = 0; g < 4; ++g) {
                    const int nt = g * 8 + ut;
                    half8 bf = *(const half8*)(whh_p + ((size_t)(nt * 4 + ks) * 64 + L) * 8);
                    acc[0][g] = __builtin_amdgcn_mfma_f32_16x16x32_f16(A[0][ks], bf, acc[0][g], 0, 0, 0);
                    acc[1][g] = __builtin_amdgcn_mfma_f32_16x16x32_f16(A[1][ks], bf, acc[1][g], 0, 0, 0);
                }
            }
            // gate nonlinearity + state update
#pragma unroll
            for (int mt = 0; mt < 2; ++mt)
#pragma unroll
                for (int r = 0; r < 4; ++r) {
                    float ii = sigf(acc[mt][0][r]);
                    float ff = sigf(acc[mt][1][r]);
                    float gg = tanh_(acc[mt][2][r]);
                    float oo = sigf(acc[mt][3][r]);
                    float cc = ff * cst[uti][mt][r] + ii * gg;
                    cst[uti][mt][r]  = cc;
                    hcur[uti][mt][r] = oo * tanh_(cc);
                }
        }
        if (st < FWn - 1) {
            _Float16* buf = hsA[st & 1];    // other buffer: no barrier needed here
#pragma unroll
            for (int uti = 0; uti < 2; ++uti) {
                const int ut = wv * 2 + uti;
                const int ks = ut >> 1;
                const int lamb = 16 * ((ut & 1) * 2 + (ln >> 3));
#pragma unroll
                for (int mt = 0; mt < 2; ++mt)
#pragma unroll
                    for (int r = 0; r < 4; ++r)
                        buf[((mt * 4 + ks) * 64 + (q * 4 + r + lamb)) * 8 + j8] =
                            (_Float16)hcur[uti][mt][r];
            }
        }
    }

    // ---- max over windows (mask invalid), reduce across quads ----
#pragma unroll
    for (int uti = 0; uti < 2; ++uti) {
        float mv = -FLT_MAX;
#pragma unroll
        for (int mt = 0; mt < 2; ++mt)
#pragma unroll
            for (int r = 0; r < 4; ++r) {
                const int w = w0 + mt * 16 + q * 4 + r;
                float hv = (w < Wn) ? hcur[uti][mt][r] : -FLT_MAX;
                mv = fmaxf(mv, hv);
            }
        mv = fmaxf(mv, __shfl_xor(mv, 16));
        mv = fmaxf(mv, __shfl_xor(mv, 32));
        if (q == 0)
            partial[(size_t)(b * NTILE + tile) * 128 + (wv * 2 + uti) * 16 + ln] = mv;
    }
}

// ---------------------------------------------------------------------------
// Kernel 3: feat[b][u] = max over tiles; out[b][c] = feat . fc_w[c] + fc_b[c]
// grid 64, block 128
// ---------------------------------------------------------------------------
__global__ void __launch_bounds__(128)
final_kernel(const float* __restrict__ partial, const float* __restrict__ fc_w,
             const float* __restrict__ fc_b, float* __restrict__ out)
{
    const int b = blockIdx.x;
    const int u = threadIdx.x;
    float m = -FLT_MAX;
#pragma unroll
    for (int tl = 0; tl < NTILE; ++tl)
        m = fmaxf(m, partial[(size_t)(b * NTILE + tl) * 128 + u]);
    float v0 = m * fc_w[u];
    float v1 = m * fc_w[128 + u];
#pragma unroll
    for (int off = 1; off < 64; off <<= 1) {
        v0 += __shfl_xor(v0, off);
        v1 += __shfl_xor(v1, off);
    }
    __shared__ float red[2][2];
    if ((u & 63) == 0) { red[u >> 6][0] = v0; red[u >> 6][1] = v1; }
    __syncthreads();
    if (u == 0) {
        out[b * 2 + 0] = red[0][0] + red[1][0] + fc_b[0];
        out[b * 2 + 1] = red[0][1] + red[1][1] + fc_b[1];
    }
}

// ---------------------------------------------------------------------------
extern "C" void kernel_launch(void* const* d_in, const int* in_sizes, int n_in,
                              void* d_out, int out_size, void* d_ws, size_t ws_size,
                              hipStream_t stream)
{
    const int*   inputs = (const int*)d_in[0];
    // d_in[1] = lengths : unused by the reference
    const float* embed  = (const float*)d_in[2];
    const float* w_ih   = (const float*)d_in[3];
    const float* w_hh   = (const float*)d_in[4];
    const float* b_ih   = (const float*)d_in[5];
    const float* b_hh   = (const float*)d_in[6];
    const float* fc_w   = (const float*)d_in[7];
    const float* fc_b   = (const float*)d_in[8];
    float* out = (float*)d_out;

    // workspace: P [32768][512] f32 (64 MiB) | partial (512 KiB) | packs (2x128 KiB)
    float*    P       = (float*)d_ws;
    float*    partial = P + (size_t)(Bn * Sn) * G4;
    _Float16* wih_p   = (_Float16*)(partial + Bn * NTILE * 128);
    _Float16* whh_p   = wih_p + 65536;

    pack_w_kernel<<<dim3(256), 256, 0, stream>>>(w_ih, w_hh, wih_p, whh_p);
    proj_kernel<<<dim3((Bn * Sn) / 32), 256, 0, stream>>>(inputs, embed, wih_p, b_ih, b_hh, P);
    lstm_kernel<<<dim3(Bn * NTILE), 256, 0, stream>>>(P, whh_p, partial);
    final_kernel<<<dim3(Bn), 128, 0, stream>>>(partial, fc_w, fc_b, out);
}

// Round 5
// 174.712 us; speedup vs baseline: 2.0949x; 1.0147x over previous
//
#include <hip/hip_runtime.h>
#include <math.h>
#include <float.h>

// Problem constants (fixed by the reference)
#define Bn   64
#define Sn   512
#define En   128
#define Hn   128
#define G4   512     // 4*H
#define FWn  6
#define Wn   507     // S - FW + 1
#define NTILE 16     // 507 windows -> 16 tiles of 32

#define XROWS   37    // rows of x staged per block (32 windows + FW-1)
#define XSTRIDE 136   // fp16 elems per x row (272 B: +16B pad -> 2-way-free reads)

typedef __attribute__((ext_vector_type(8))) _Float16 half8;
typedef __attribute__((ext_vector_type(4))) float f32x4;

// Fast activations: v_exp_f32 + v_rcp_f32 (1 ulp), NaN-free at extremes.
__device__ __forceinline__ float sigf(float x)  {
    return __builtin_amdgcn_rcpf(1.0f + __expf(-x));
}
__device__ __forceinline__ float tanh_(float x) {
    return 1.0f - 2.0f * __builtin_amdgcn_rcpf(__expf(2.0f * x) + 1.0f);
}

// ---------------------------------------------------------------------------
// Kernel 0: pack w_ih and w_hh (both [512][128] f32) into fp16 B-fragment
// order for mfma_f32_16x16x32_f16:
//   pack[((nt*4 + ks)*64 + lane)*8 + j] = w[nt*16 + (lane&15)][ks*32 + (lane>>4)*8 + j]
// Row-tile nt = g*8 + ut (gate g, unit-tile ut). 65536 elements each.
// ---------------------------------------------------------------------------
__global__ void __launch_bounds__(256)
pack_w_kernel(const float* __restrict__ w_ih, const float* __restrict__ w_hh,
              _Float16* __restrict__ wih_p, _Float16* __restrict__ whh_p)
{
    const int idx = blockIdx.x * 256 + threadIdx.x;      // 0..65535
    const int j  = idx & 7;
    const int L  = (idx >> 3) & 63;
    const int ks = (idx >> 9) & 3;
    const int nt = idx >> 11;
    const int row = nt * 16 + (L & 15);
    const int col = ks * 32 + (L >> 4) * 8 + j;
    wih_p[idx] = (_Float16)w_ih[row * 128 + col];
    whh_p[idx] = (_Float16)w_hh[row * 128 + col];
}

// ---------------------------------------------------------------------------
// Kernel 1 (fused MFMA LSTM): 32 windows per block, 6 steps.
//   - x rows [w0, w0+36] staged once into LDS as fp16 (A-operand row-major,
//     row stride 272 B). Input projection recomputed per step via MFMA
//     (C init = bias, fp32 accumulate) — removes the P workspace entirely.
//   - h double-buffered in LDS in A-fragment order, 1 barrier/step.
//   - w_ih/w_hh B-fragments from packed fp16 (L2-resident, 128 KB each).
//   NOTE: no min-waves launch bound — R3 showed a forced VGPR cap (144->64)
//   causes catastrophic scratch spill (251 MB).
// grid 64*16, block 256.
// ---------------------------------------------------------------------------
__global__ void __launch_bounds__(256)
lstm_kernel(const int* __restrict__ inputs, const float* __restrict__ embed,
            const _Float16* __restrict__ wih_p, const _Float16* __restrict__ whh_p,
            const float* __restrict__ b_ih, const float* __restrict__ b_hh,
            float* __restrict__ partial)
{
    __shared__ __align__(16) _Float16 x_win[XROWS * XSTRIDE];  // 9.9 KB
    __shared__ __align__(16) _Float16 hsA[2][4096];            // 2 x 8 KB
    const int t    = threadIdx.x;
    const int L    = t & 63;
    const int wv   = t >> 6;
    const int b    = blockIdx.x >> 4;
    const int tile = blockIdx.x & 15;
    const int w0   = tile * 32;
    const int q  = L >> 4;
    const int ln = L & 15;
    const int j8 = L & 7;

    // ---- stage x rows (gather embed, cvt fp16) ----
    {
        const int rr = t >> 3;          // 0..31
        const int lc = t & 7;           // 16-float chunk within row
#pragma unroll
        for (int base = 0; base < XROWS; base += 32) {
            const int i = base + rr;
            if (i < XROWS) {
                int s = w0 + i; s = s < 511 ? s : 511;   // clamp (masked at max)
                const int tok = inputs[b * Sn + s];
                const float* er = embed + (size_t)tok * 128 + lc * 16;
                float4 e0 = *(const float4*)(er);
                float4 e1 = *(const float4*)(er + 4);
                float4 e2 = *(const float4*)(er + 8);
                float4 e3 = *(const float4*)(er + 12);
                half8 h0, h1;
                h0[0] = (_Float16)e0.x; h0[1] = (_Float16)e0.y;
                h0[2] = (_Float16)e0.z; h0[3] = (_Float16)e0.w;
                h0[4] = (_Float16)e1.x; h0[5] = (_Float16)e1.y;
                h0[6] = (_Float16)e1.z; h0[7] = (_Float16)e1.w;
                h1[0] = (_Float16)e2.x; h1[1] = (_Float16)e2.y;
                h1[2] = (_Float16)e2.z; h1[3] = (_Float16)e2.w;
                h1[4] = (_Float16)e3.x; h1[5] = (_Float16)e3.y;
                h1[6] = (_Float16)e3.z; h1[7] = (_Float16)e3.w;
                *(half8*)&x_win[i * XSTRIDE + lc * 16]     = h0;
                *(half8*)&x_win[i * XSTRIDE + lc * 16 + 8] = h1;
            }
        }
    }

    // per-lane gate biases for this wave's 2 unit-tiles
    float biasg[2][4];
#pragma unroll
    for (int uti = 0; uti < 2; ++uti) {
        const int u = (wv * 2 + uti) * 16 + ln;
#pragma unroll
        for (int g = 0; g < 4; ++g)
            biasg[uti][g] = b_ih[g * 128 + u] + b_hh[g * 128 + u];
    }

    float cst[2][2][4];    // [uti][mt][r]
    float hcur[2][2][4];
#pragma unroll
    for (int uti = 0; uti < 2; ++uti)
#pragma unroll
        for (int mt = 0; mt < 2; ++mt)
#pragma unroll
            for (int r = 0; r < 4; ++r) cst[uti][mt][r] = 0.0f;

    __syncthreads();       // x_win staged

    // ---- steps 0..5 ----
    for (int st = 0; st < FWn; ++st) {
        if (st > 0) __syncthreads();            // h writes of prev step visible
        const _Float16* hb = hsA[(st + 1) & 1]; // buffer written at end of st-1

#pragma unroll
        for (int uti = 0; uti < 2; ++uti) {
            const int ut = wv * 2 + uti;
            f32x4 acc[2][4];                // [mt][gate]
#pragma unroll
            for (int mt = 0; mt < 2; ++mt)
#pragma unroll
                for (int g = 0; g < 4; ++g) {
                    const float bg = biasg[uti][g];
                    acc[mt][g] = (f32x4){bg, bg, bg, bg};
                }
            // input projection: x rows [st + mt*16 + m]
#pragma unroll
            for (int ks = 0; ks < 4; ++ks) {
                half8 ax0 = *(const half8*)&x_win[(st + ln) * XSTRIDE + ks * 32 + q * 8];
                half8 ax1 = *(const half8*)&x_win[(st + 16 + ln) * XSTRIDE + ks * 32 + q * 8];
#pragma unroll
                for (int g = 0; g < 4; ++g) {
                    const int nt = g * 8 + ut;
                    half8 bw = *(const half8*)(wih_p + ((size_t)(nt * 4 + ks) * 64 + L) * 8);
                    acc[0][g] = __builtin_amdgcn_mfma_f32_16x16x32_f16(ax0, bw, acc[0][g], 0, 0, 0);
                    acc[1][g] = __builtin_amdgcn_mfma_f32_16x16x32_f16(ax1, bw, acc[1][g], 0, 0, 0);
                }
            }
            // hidden projection (skip at st=0: h=0)
            if (st > 0) {
#pragma unroll
                for (int ks = 0; ks < 4; ++ks) {
                    half8 ah0 = *(const half8*)(hb + ((0 * 4 + ks) * 64 + L) * 8);
                    half8 ah1 = *(const half8*)(hb + ((1 * 4 + ks) * 64 + L) * 8);
#pragma unroll
                    for (int g = 0; g < 4; ++g) {
                        const int nt = g * 8 + ut;
                        half8 bh = *(const half8*)(whh_p + ((size_t)(nt * 4 + ks) * 64 + L) * 8);
                        acc[0][g] = __builtin_amdgcn_mfma_f32_16x16x32_f16(ah0, bh, acc[0][g], 0, 0, 0);
                        acc[1][g] = __builtin_amdgcn_mfma_f32_16x16x32_f16(ah1, bh, acc[1][g], 0, 0, 0);
                    }
                }
            }
            // gate nonlinearity + state update (st=0: cst=0 so f-term drops)
#pragma unroll
            for (int mt = 0; mt < 2; ++mt)
#pragma unroll
                for (int r = 0; r < 4; ++r) {
                    float ii = sigf(acc[mt][0][r]);
                    float ff = sigf(acc[mt][1][r]);
                    float gg = tanh_(acc[mt][2][r]);
                    float oo = sigf(acc[mt][3][r]);
                    float cc = ff * cst[uti][mt][r] + ii * gg;
                    cst[uti][mt][r]  = cc;
                    hcur[uti][mt][r] = oo * tanh_(cc);
                }
        }
        if (st < FWn - 1) {
            _Float16* buf = hsA[st & 1];    // other buffer: no barrier needed here
#pragma unroll
            for (int uti = 0; uti < 2; ++uti) {
                const int ut = wv * 2 + uti;
                const int ks = ut >> 1;
                const int lamb = 16 * ((ut & 1) * 2 + (ln >> 3));
#pragma unroll
                for (int mt = 0; mt < 2; ++mt)
#pragma unroll
                    for (int r = 0; r < 4; ++r)
                        buf[((mt * 4 + ks) * 64 + (q * 4 + r + lamb)) * 8 + j8] =
                            (_Float16)hcur[uti][mt][r];
            }
        }
    }

    // ---- max over windows (mask invalid), reduce across quads ----
#pragma unroll
    for (int uti = 0; uti < 2; ++uti) {
        float mv = -FLT_MAX;
#pragma unroll
        for (int mt = 0; mt < 2; ++mt)
#pragma unroll
            for (int r = 0; r < 4; ++r) {
                const int w = w0 + mt * 16 + q * 4 + r;
                float hv = (w < Wn) ? hcur[uti][mt][r] : -FLT_MAX;
                mv = fmaxf(mv, hv);
            }
        mv = fmaxf(mv, __shfl_xor(mv, 16));
        mv = fmaxf(mv, __shfl_xor(mv, 32));
        if (q == 0)
            partial[(size_t)(b * NTILE + tile) * 128 + (wv * 2 + uti) * 16 + ln] = mv;
    }
}

// ---------------------------------------------------------------------------
// Kernel 2: feat[b][u] = max over tiles; out[b][c] = feat . fc_w[c] + fc_b[c]
// grid 64, block 128
// ---------------------------------------------------------------------------
__global__ void __launch_bounds__(128)
final_kernel(const float* __restrict__ partial, const float* __restrict__ fc_w,
             const float* __restrict__ fc_b, float* __restrict__ out)
{
    const int b = blockIdx.x;
    const int u = threadIdx.x;
    float m = -FLT_MAX;
#pragma unroll
    for (int tl = 0; tl < NTILE; ++tl)
        m = fmaxf(m, partial[(size_t)(b * NTILE + tl) * 128 + u]);
    float v0 = m * fc_w[u];
    float v1 = m * fc_w[128 + u];
#pragma unroll
    for (int off = 1; off < 64; off <<= 1) {
        v0 += __shfl_xor(v0, off);
        v1 += __shfl_xor(v1, off);
    }
    __shared__ float red[2][2];
    if ((u & 63) == 0) { red[u >> 6][0] = v0; red[u >> 6][1] = v1; }
    __syncthreads();
    if (u == 0) {
        out[b * 2 + 0] = red[0][0] + red[1][0] + fc_b[0];
        out[b * 2 + 1] = red[0][1] + red[1][1] + fc_b[1];
    }
}

// ---------------------------------------------------------------------------
extern "C" void kernel_launch(void* const* d_in, const int* in_sizes, int n_in,
                              void* d_out, int out_size, void* d_ws, size_t ws_size,
                              hipStream_t stream)
{
    const int*   inputs = (const int*)d_in[0];
    // d_in[1] = lengths : unused by the reference
    const float* embed  = (const float*)d_in[2];
    const float* w_ih   = (const float*)d_in[3];
    const float* w_hh   = (const float*)d_in[4];
    const float* b_ih   = (const float*)d_in[5];
    const float* b_hh   = (const float*)d_in[6];
    const float* fc_w   = (const float*)d_in[7];
    const float* fc_b   = (const float*)d_in[8];
    float* out = (float*)d_out;

    // workspace: partial (512 KiB) | wih_p, whh_p (128 KiB each)
    float*    partial = (float*)d_ws;
    _Float16* wih_p   = (_Float16*)(partial + Bn * NTILE * 128);
    _Float16* whh_p   = wih_p + 65536;

    pack_w_kernel<<<dim3(256), 256, 0, stream>>>(w_ih, w_hh, wih_p, whh_p);
    lstm_kernel<<<dim3(Bn * NTILE), 256, 0, stream>>>(inputs, embed, wih_p, whh_p,
                                                      b_ih, b_hh, partial);
    final_kernel<<<dim3(Bn), 128, 0, stream>>>(partial, fc_w, fc_b, out);
}